// Round 8
// baseline (206.467 us; speedup 1.0000x reference)
//
#include <hip/hip_runtime.h>
#include <hip/hip_bf16.h>
#include <cstdint>

typedef unsigned short u16;
typedef __attribute__((ext_vector_type(8))) short bf16x8;
typedef __attribute__((ext_vector_type(4))) float f32x4;
typedef __attribute__((ext_vector_type(16))) float f32x16;

#define T_SEQ 2048
#define NHEAD 16
#define HDIM  64
#define NB    2

__device__ __forceinline__ float bf2f(uint32_t h) { return __uint_as_float(h << 16); }
__device__ __forceinline__ u16 f2bf(float f) {
    uint32_t u = __float_as_uint(f);
    u += 0x7fffu + ((u >> 16) & 1u);
    return (u16)(u >> 16);
}

// v_cvt_pk_bf16_f32: pack two f32 -> one u32 of 2 bf16 (RNE). No builtin on
// gfx950 (learn_hip m240); inline asm is the guide-verified recipe.
__device__ __forceinline__ uint32_t cvt_pk_bf16(float lo, float hi) {
    uint32_t r;
    asm("v_cvt_pk_bf16_f32 %0, %1, %2" : "=v"(r) : "v"(lo), "v"(hi));
    return r;
}

// async global->LDS, 16B per lane; LDS dest = wave-uniform base + lane*16
__device__ __forceinline__ void gl_lds16(const u16* g, u16* s) {
    __builtin_amdgcn_global_load_lds(
        (const __attribute__((address_space(1))) unsigned int*)g,
        (__attribute__((address_space(3))) unsigned int*)s, 16, 0, 0);
}

// Detect input dtype (parallel): bf16-packed data has low-u16 exponent fields
// clustered near 127; fp32 low halves are ~uniform mantissa bits.
__global__ void detect_dtype(const uint32_t* __restrict__ x, int* __restrict__ flag) {
    __shared__ int red[4];
    int c = 0;
#pragma unroll
    for (int j = 0; j < 4; j++) {
        uint32_t v = x[threadIdx.x * 4 + j];
        uint32_t lo = v & 0xffffu;
        uint32_t e = (lo >> 7) & 0xffu;
        if (lo != 0u && e >= 110u && e <= 135u) c++;
    }
#pragma unroll
    for (int off = 32; off; off >>= 1) c += __shfl_down(c, off);
    if ((threadIdx.x & 63) == 0) red[threadIdx.x >> 6] = c;
    __syncthreads();
    if (threadIdx.x == 0)
        *flag = (red[0] + red[1] + red[2] + red[3] > 614) ? 1 : 0;   // 1=bf16, 0=fp32
}

// vectorized conversion, 4 elements per thread
__global__ __launch_bounds__(256) void to_bf16(
    const void* __restrict__ src, u16* __restrict__ dst, int n4,
    const int* __restrict__ flag)
{
    int i = blockIdx.x * 256 + threadIdx.x;
    const int stride = gridDim.x * 256;
    if (*flag != 0) {
        const uint2* s = (const uint2*)src;
        uint2* d = (uint2*)dst;
        for (; i < n4; i += stride) d[i] = s[i];
    } else {
        const float4* s = (const float4*)src;
        for (; i < n4; i += stride) {
            float4 v = s[i];
            ushort4 o = { f2bf(v.x), f2bf(v.y), f2bf(v.z), f2bf(v.w) };
            *(ushort4*)(dst + (size_t)i * 4) = o;
        }
    }
}

// m97-pattern MFMA GEMM: C = A (MxK bf16 rm) * B^T (B NxK rm), fp32 accum.
// global_load_lds width-16 staging into unpadded [BM][64] LDS tiles with XOR
// swizzle -> conflict-free stride-64 fragment reads. 4 waves in 2x2.
// MODE 0 (BM=128): scatter q [b,h,t,d] (x0.125), k [b,h,t,d], vT [b,h,d,t].
// MODE 1 (BM=64): row-major C; fp32 (flag==0) or bf16 path, full-line stores.
template<int BM, int MODE>
__global__ __launch_bounds__(256, 3) void gemm_bt_mfma(
    const u16* __restrict__ A, const u16* __restrict__ B,
    int N, int K,
    u16* __restrict__ qo, u16* __restrict__ ko, u16* __restrict__ vt,
    u16* __restrict__ outb16, float* __restrict__ outf32,
    const int* __restrict__ flag)
{
    constexpr int WM = BM / 2;
    constexpr int MI = WM / 16;
    constexpr int IA = BM / 32;
    constexpr int ST = 2 * BM * 64 * 2;
    constexpr int E16 = 4 * WM * 72 * 2;
    constexpr int EF = (MODE == 1) ? 4 * WM * (WM + 4) * 4 : 0;
    constexpr int SB = (ST > E16 ? ST : E16) > EF ? (ST > E16 ? ST : E16) : EF;
    __shared__ u16 smem[SB / 2];
    u16* As = smem;            // [BM][64]
    u16* Bs = smem + BM * 64;  // [BM][64]
    const int tid = threadIdx.x;
    const int bm = blockIdx.y * BM, bn = blockIdx.x * BM;
    const int w = tid >> 6, lane = tid & 63;
    const int wm = (w >> 1) * WM, wn = (w & 1) * WM;
    const int n16 = lane & 15, quad = lane >> 4;
    const int l8 = lane >> 3, c8 = lane & 7;

    f32x4 acc[MI][MI];
#pragma unroll
    for (int mi = 0; mi < MI; mi++)
#pragma unroll
        for (int ni = 0; ni < MI; ni++) acc[mi][ni] = (f32x4){0.f, 0.f, 0.f, 0.f};

    const int KT = K >> 6;
    for (int kt = 0; kt < KT; kt++) {
        const int k0 = kt << 6;
#pragma unroll
        for (int i = 0; i < IA; i++) {
            int rowblk = (i * 4 + w) * 8;
            int row = rowblk + l8;
            int gcol = (c8 ^ l8) * 8;   // XOR swizzle
            gl_lds16(A + (size_t)(bm + row) * K + k0 + gcol, As + rowblk * 64);
            gl_lds16(B + (size_t)(bn + row) * K + k0 + gcol, Bs + rowblk * 64);
        }
        __syncthreads();
#pragma unroll
        for (int ks = 0; ks < 2; ks++) {
            bf16x8 af[MI], bfr[MI];
#pragma unroll
            for (int mi = 0; mi < MI; mi++) {
                int row = wm + mi * 16 + n16;
                af[mi] = *(const bf16x8*)(As + row * 64 + (((ks * 4 + quad) ^ (n16 & 7)) * 8));
            }
#pragma unroll
            for (int ni = 0; ni < MI; ni++) {
                int row = wn + ni * 16 + n16;
                bfr[ni] = *(const bf16x8*)(Bs + row * 64 + (((ks * 4 + quad) ^ (n16 & 7)) * 8));
            }
#pragma unroll
            for (int mi = 0; mi < MI; mi++)
#pragma unroll
                for (int ni = 0; ni < MI; ni++)
                    acc[mi][ni] = __builtin_amdgcn_mfma_f32_16x16x32_bf16(
                        af[mi], bfr[ni], acc[mi][ni], 0, 0, 0);
        }
        __syncthreads();
    }

    // Epilogues: per-wave LDS transpose -> full-line stores.
    // C/D layout: col = n16, row = quad*4 + r (HW-verified m89/m91).
    if constexpr (MODE == 0) {
        u16* ep = smem + w * (WM * 72);
        const int which = (bn + wn) >> 10;            // 0=q 1=k 2=v (wave-uniform)
        const int hq = ((bn + wn) & 1023) >> 6;
        const int bb = (bm + wm) >> 11;
        const int tb = (bm + wm) & (T_SEQ - 1);
        if (which == 2) {
#pragma unroll
            for (int mi = 0; mi < MI; mi++)
#pragma unroll
                for (int ni = 0; ni < MI; ni++)
#pragma unroll
                    for (int r = 0; r < 4; r++)
                        ep[(ni * 16 + n16) * 72 + mi * 16 + quad * 4 + r] = f2bf(acc[mi][ni][r]);
            asm volatile("s_waitcnt lgkmcnt(0)" ::: "memory");
            u16* dst = vt + ((size_t)(bb * NHEAD + hq) * HDIM) * T_SEQ + tb;
#pragma unroll
            for (int it = 0; it < 8; it++) {
                int row = it * 8 + l8, col = c8 * 8;
                bf16x8 v = *(const bf16x8*)(ep + row * 72 + col);
                *(bf16x8*)(dst + (size_t)row * T_SEQ + col) = v;
            }
        } else {
            const float sc = which ? 1.f : 0.125f;
#pragma unroll
            for (int mi = 0; mi < MI; mi++)
#pragma unroll
                for (int ni = 0; ni < MI; ni++)
#pragma unroll
                    for (int r = 0; r < 4; r++)
                        ep[(mi * 16 + quad * 4 + r) * 72 + ni * 16 + n16] = f2bf(acc[mi][ni][r] * sc);
            asm volatile("s_waitcnt lgkmcnt(0)" ::: "memory");
            u16* dst = (which ? ko : qo) + ((size_t)(bb * NHEAD + hq) * T_SEQ + tb) * HDIM;
#pragma unroll
            for (int it = 0; it < 8; it++) {
                int row = it * 8 + l8, col = c8 * 8;
                bf16x8 v = *(const bf16x8*)(ep + row * 72 + col);
                *(bf16x8*)(dst + (size_t)row * HDIM + col) = v;
            }
        }
    } else {
        if (*flag == 0) {
            float* epf = (float*)smem + w * (WM * (WM + 4));
#pragma unroll
            for (int mi = 0; mi < MI; mi++)
#pragma unroll
                for (int ni = 0; ni < MI; ni++)
#pragma unroll
                    for (int r = 0; r < 4; r++)
                        epf[(mi * 16 + quad * 4 + r) * (WM + 4) + ni * 16 + n16] = acc[mi][ni][r];
            asm volatile("s_waitcnt lgkmcnt(0)" ::: "memory");
            constexpr int LPR = WM / 4;
            constexpr int RPI = 64 / LPR;
#pragma unroll
            for (int it = 0; it < WM / RPI; it++) {
                int row = it * RPI + lane / LPR, col = (lane % LPR) * 4;
                float4 v = *(const float4*)(epf + row * (WM + 4) + col);
                *(float4*)(outf32 + (size_t)(bm + wm + row) * N + bn + wn + col) = v;
            }
        } else {
            u16* ep = smem + w * (WM * 72);
#pragma unroll
            for (int mi = 0; mi < MI; mi++)
#pragma unroll
                for (int ni = 0; ni < MI; ni++)
#pragma unroll
                    for (int r = 0; r < 4; r++)
                        ep[(mi * 16 + quad * 4 + r) * 72 + ni * 16 + n16] = f2bf(acc[mi][ni][r]);
            asm volatile("s_waitcnt lgkmcnt(0)" ::: "memory");
            constexpr int LPR = WM / 8;
            constexpr int RPI = 64 / LPR;
#pragma unroll
            for (int it = 0; it < WM / RPI; it++) {
                int row = it * RPI + lane / LPR, col = (lane % LPR) * 8;
                bf16x8 v = *(const bf16x8*)(ep + row * 72 + col);
                *(bf16x8*)(outb16 + (size_t)(bm + wm + row) * N + bn + wn + col) = v;
            }
        }
    }
}

// MFMA flash attention v8: swapped-QK 32x32 MFMA + fully in-register softmax.
// R0-R7 post-mortem: every variant shared the P-LDS round trip (16 scalar
// ds_write_b16 -> lgkmcnt(0) drain -> ds_read_b128) per 16-q-row subtile —
// ~400-500 cy of unhideable serial latency inside a barrier convoy; durations
// were flat (47-56 us) across 8x occupancy and 2x traffic changes. v8 removes
// that chain segment entirely (T12, learn_hip m214v22):
//  * QK^T computed SWAPPED: S = mfma_32x32x16(K_frag, Q_frag) -> lane holds
//    S[kt][q= lane&31]: each lane owns a full P-row slice for ONE q-row.
//  * softmax in registers (exp2, max-free p=e^{S-10}); P->bf16 via
//    v_cvt_pk_bf16_f32; cross-half redistribution with TWO
//    __builtin_amdgcn_permlane32_swap per 16-kt step ("one swap fills two
//    output words"): pf = [x(c0,c2), x(c1,c3), y(c0,c2), y(c1,c3)].
//  * PV: accO = mfma(pf, V^T_frag); denominators accL = mfma(pf, ones) —
//    same rounded-P numerics as before, and accL rows align with accO rows
//    (both crow(r,h)) so the epilogue needs no cross-lane L exchange.
// Geometry: 4 waves x 32 q-rows = 128-row q-block; KV tile 64; R1's grid/
// mapping/staging/2-barrier loop (the reproducible best). Frag reads per
// q-row HALVE vs R1 (16 b128 now feed 32 rows). LDS 34.8 KB (16 staging +
// 18 epilogue), no Plds. XCD pinning: bh = bidx&31 -> xcd = bidx&7 = bh&7.
__global__ __launch_bounds__(256, 3) void attn_mfma(
    const u16* __restrict__ qb, const u16* __restrict__ kb,
    const u16* __restrict__ vt, u16* __restrict__ ob)
{
    __shared__ u16 Ks[64 * 64];        // [t_local][d], XOR-swizzled chunks
    __shared__ u16 Vs[64 * 64];        // [d][t_local], XOR-swizzled chunks
    __shared__ u16 Ep[4][32][72];      // per-wave epilogue transpose buffer
    const int bidx = blockIdx.x;       // 0..511
    const int c = bidx & 255;
    const int rr = bidx >> 8;          // round 0/1
    const int bh = c & 31;             // xcd = bidx&7 = bh&7 (pinned)
    const int jm = c >> 5;             // 0..7
    const int t = rr ? (15 - jm) : jm; // q-block 0..15
    const int w = threadIdx.x >> 6, lane = threadIdx.x & 63;
    const int l31 = lane & 31, h = lane >> 5;
    const int l8 = lane >> 3, c8 = lane & 7;
    const size_t baseK = (size_t)bh * T_SEQ * HDIM;   // [t][d]
    const size_t baseV = (size_t)bh * HDIM * T_SEQ;   // [d][t]
    const int b = bh >> 4, head = bh & 15;

    bf16x8 ones;
#pragma unroll
    for (int e = 0; e < 8; e++) ones[e] = (short)0x3F80;   // bf16 1.0

    // 4 waves stage one 64x64 K tile + one 64x64 V^T tile (two 8-row chunks
    // per tensor per wave). LDS[row][chunk c] = global[row][(c^(row&7))*8].
    auto stage = [&](int kt) {
#pragma unroll
        for (int i = 0; i < 2; i++) {
            int rowblk = w * 16 + i * 8;
            int row = rowblk + l8;
            int gc = (c8 ^ l8) * 8;    // XOR swizzle
            gl_lds16(kb + baseK + (size_t)(kt * 64 + row) * HDIM + gc, Ks + rowblk * 64);
            gl_lds16(vt + baseV + (size_t)row * T_SEQ + (size_t)kt * 64 + gc, Vs + rowblk * 64);
        }
    };

    // Q as the B-operand: B[n=q][k=d]: lane holds Q[qrow+l31][ds*16 + h*8 + j]
    const int qrow = t * 128 + w * 32;
    bf16x8 qf[4];
#pragma unroll
    for (int ds = 0; ds < 4; ds++)
        qf[ds] = *(const bf16x8*)(qb + baseK + (size_t)(qrow + l31) * HDIM + ds * 16 + h * 8);

    f32x16 accO0 = (f32x16)0.f;        // O[q=crow(r,h)][d =      l31]
    f32x16 accO1 = (f32x16)0.f;        // O[q=crow(r,h)][d = 32 + l31]
    f32x16 accL  = (f32x16)0.f;        // L[q=crow(r,h)] (all cols equal)

    const int ktmax = 2 * t + 1;           // block's last staged tile
    const int kend  = 2 * t + (w >> 1);    // this wave's diagonal tile

    stage(0);
    for (int kt = 0; kt <= ktmax; kt++) {
        __syncthreads();                   // stage(kt) complete (drains vmcnt)

        const bool act = (kt <= kend);     // wave-uniform
        f32x16 S0 = (f32x16)0.f, S1 = (f32x16)0.f;
        bf16x8 vf[2][4];
        if (act) {
            // Swapped QK: A = K-frag (m=kt, k=d), B = Q-frag (n=q, k=d).
#pragma unroll
            for (int ds = 0; ds < 4; ds++) {
                const int g = ds * 2 + h;
                bf16x8 ka = *(const bf16x8*)(Ks + l31 * 64 + ((g ^ (l31 & 7)) * 8));
                bf16x8 kc = *(const bf16x8*)(Ks + (32 + l31) * 64 + ((g ^ (l31 & 7)) * 8));
                S0 = __builtin_amdgcn_mfma_f32_32x32x16_bf16(ka, qf[ds], S0, 0, 0, 0);
                S1 = __builtin_amdgcn_mfma_f32_32x32x16_bf16(kc, qf[ds], S1, 0, 0, 0);
            }
            // V^T as B-operand: B[n=d][k=kt]; read all before KV is restaged.
#pragma unroll
            for (int dblk = 0; dblk < 2; dblk++)
#pragma unroll
                for (int ks = 0; ks < 4; ks++) {
                    const int row = dblk * 32 + l31;
                    const int g = ks * 2 + h;
                    vf[dblk][ks] = *(const bf16x8*)(Vs + row * 64 + ((g ^ (row & 7)) * 8));
                }
        }
        __syncthreads();                   // fragments in registers; K/V LDS free

        if (kt < ktmax) stage(kt + 1);     // async, lands during compute below

        if (act) {
            if (kt == kend) {
                const int ql = (w & 1) * 32 + l31;   // q pos in the 64-window
#pragma unroll
                for (int r = 0; r < 16; r++) {
                    const int row = (r & 3) + ((r >> 2) << 3) + 4 * h;  // kt_local
                    if (row > ql)      S0[r] = -INFINITY;
                    if (row + 32 > ql) S1[r] = -INFINITY;
                }
            }
#pragma unroll
            for (int r = 0; r < 16; r++) {
                S0[r] = exp2f(__builtin_fmaf(S0[r], 1.44269504f, -14.4269504f));
                S1[r] = exp2f(__builtin_fmaf(S1[r], 1.44269504f, -14.4269504f));
            }
            // Pack P rows to bf16 A-frags: per 16-kt step, lane needs
            // P[q][step*16 + h*8 + j]. cvt_pk pairs + permlane32_swap:
            // frag = [x(c0,c2), x(c1,c3), y(c0,c2), y(c1,c3)].
            bf16x8 pf[4];
#pragma unroll
            for (int half = 0; half < 2; half++) {
                {
                    uint32_t c0 = cvt_pk_bf16(S0[half * 8 + 0], S0[half * 8 + 1]);
                    uint32_t c1 = cvt_pk_bf16(S0[half * 8 + 2], S0[half * 8 + 3]);
                    uint32_t c2 = cvt_pk_bf16(S0[half * 8 + 4], S0[half * 8 + 5]);
                    uint32_t c3 = cvt_pk_bf16(S0[half * 8 + 6], S0[half * 8 + 7]);
                    auto s0 = __builtin_amdgcn_permlane32_swap(c0, c2, false, false);
                    auto s1 = __builtin_amdgcn_permlane32_swap(c1, c3, false, false);
                    union { uint32_t u[4]; bf16x8 v; } uu;
                    uu.u[0] = s0[0]; uu.u[1] = s1[0]; uu.u[2] = s0[1]; uu.u[3] = s1[1];
                    pf[half] = uu.v;
                }
                {
                    uint32_t c0 = cvt_pk_bf16(S1[half * 8 + 0], S1[half * 8 + 1]);
                    uint32_t c1 = cvt_pk_bf16(S1[half * 8 + 2], S1[half * 8 + 3]);
                    uint32_t c2 = cvt_pk_bf16(S1[half * 8 + 4], S1[half * 8 + 5]);
                    uint32_t c3 = cvt_pk_bf16(S1[half * 8 + 6], S1[half * 8 + 7]);
                    auto s0 = __builtin_amdgcn_permlane32_swap(c0, c2, false, false);
                    auto s1 = __builtin_amdgcn_permlane32_swap(c1, c3, false, false);
                    union { uint32_t u[4]; bf16x8 v; } uu;
                    uu.u[0] = s0[0]; uu.u[1] = s1[0]; uu.u[2] = s0[1]; uu.u[3] = s1[1];
                    pf[2 + half] = uu.v;
                }
            }
            // PV + denominators: A = P-frag (m=q, k=kt), B = V^T / ones.
#pragma unroll
            for (int ks = 0; ks < 4; ks++) {
                accL  = __builtin_amdgcn_mfma_f32_32x32x16_bf16(pf[ks], ones,       accL,  0, 0, 0);
                accO0 = __builtin_amdgcn_mfma_f32_32x32x16_bf16(pf[ks], vf[0][ks], accO0, 0, 0, 0);
                accO1 = __builtin_amdgcn_mfma_f32_32x32x16_bf16(pf[ks], vf[1][ks], accO1, 0, 0, 0);
            }
        }
    }

    // epilogue: normalize (accL rows align with accO rows), transpose via
    // wave-private Ep, full-line global stores.
    u16* ep = &Ep[w][0][0];
#pragma unroll
    for (int r = 0; r < 16; r++) {
        const int row = (r & 3) + ((r >> 2) << 3) + 4 * h;   // q_local
        const float inv = 1.f / accL[r];
        ep[row * 72 + l31]      = f2bf(accO0[r] * inv);
        ep[row * 72 + 32 + l31] = f2bf(accO1[r] * inv);
    }
    asm volatile("s_waitcnt lgkmcnt(0)" ::: "memory");
    u16* dst = ob + ((size_t)(b * T_SEQ + qrow)) * 1024 + head * HDIM;
#pragma unroll
    for (int it = 0; it < 4; it++) {
        int row = it * 8 + l8, col = c8 * 8;
        bf16x8 v = *(const bf16x8*)(ep + row * 72 + col);
        *(bf16x8*)(dst + (size_t)row * 1024 + col) = v;
    }
}

extern "C" void kernel_launch(void* const* d_in, const int* in_sizes, int n_in,
                              void* d_out, int out_size, void* d_ws, size_t ws_size,
                              hipStream_t stream) {
    const void* x    = d_in[0];   // (2,2048,1024)
    const void* Wqkv = d_in[1];   // (3072,1024)
    const void* Wout = d_in[2];   // (1024,1024)

    const int Mtok = NB * T_SEQ;                                  // 4096
    const size_t n_x    = (size_t)Mtok * 1024;
    const size_t n_wqkv = (size_t)3072 * 1024;
    const size_t n_wout = (size_t)1024 * 1024;
    const size_t qkv_elems = (size_t)NB * NHEAD * T_SEQ * HDIM;   // 4,194,304

    u16* xb    = (u16*)d_ws;
    u16* wqkvb = xb + n_x;
    u16* woutb = wqkvb + n_wqkv;
    u16* qb    = woutb + n_wout;
    u16* kb    = qb + qkv_elems;
    u16* vt    = kb + qkv_elems;   // V stored transposed [b,h,d,t]
    u16* obuf  = vt + qkv_elems;
    int* flag  = (int*)(obuf + qkv_elems);

    detect_dtype<<<1, 256, 0, stream>>>((const uint32_t*)x, flag);

    to_bf16<<<1024, 256, 0, stream>>>(x,    xb,    (int)(n_x / 4),    flag);
    to_bf16<<<1024, 256, 0, stream>>>(Wqkv, wqkvb, (int)(n_wqkv / 4), flag);
    to_bf16<<<512,  256, 0, stream>>>(Wout, woutb, (int)(n_wout / 4), flag);

    gemm_bt_mfma<128, 0><<<dim3(3072 / 128, Mtok / 128), 256, 0, stream>>>(
        xb, wqkvb, 3072, 1024, qb, kb, vt, nullptr, nullptr, flag);

    // 512 blocks x 256 threads: 32 bh x 16 q-blocks of 128 rows, 4 waves each;
    // 32x32 MFMA, softmax fully in-register (no P LDS round trip)
    attn_mfma<<<dim3(NB * NHEAD * (T_SEQ / 128)), 256, 0, stream>>>(qb, kb, vt, obuf);

    gemm_bt_mfma<64, 1><<<dim3(1024 / 64, Mtok / 64), 256, 0, stream>>>(
        obuf, woutb, 1024, 1024, nullptr, nullptr, nullptr,
        (u16*)d_out, (float*)d_out, flag);
}

// Round 9
// 177.249 us; speedup vs baseline: 1.1648x; 1.1648x over previous
//
#include <hip/hip_runtime.h>
#include <hip/hip_bf16.h>
#include <cstdint>

typedef unsigned short u16;
typedef __attribute__((ext_vector_type(8))) short bf16x8;
typedef __attribute__((ext_vector_type(4))) float f32x4;

#define T_SEQ 2048
#define NHEAD 16
#define HDIM  64
#define NB    2

__device__ __forceinline__ float bf2f(uint32_t h) { return __uint_as_float(h << 16); }
__device__ __forceinline__ u16 f2bf(float f) {
    uint32_t u = __float_as_uint(f);
    u += 0x7fffu + ((u >> 16) & 1u);
    return (u16)(u >> 16);
}

// async global->LDS, 16B per lane; LDS dest = wave-uniform base + lane*16
__device__ __forceinline__ void gl_lds16(const u16* g, u16* s) {
    __builtin_amdgcn_global_load_lds(
        (const __attribute__((address_space(1))) unsigned int*)g,
        (__attribute__((address_space(3))) unsigned int*)s, 16, 0, 0);
}

// Detect input dtype (parallel): bf16-packed data has low-u16 exponent fields
// clustered near 127; fp32 low halves are ~uniform mantissa bits.
__global__ void detect_dtype(const uint32_t* __restrict__ x, int* __restrict__ flag) {
    __shared__ int red[4];
    int c = 0;
#pragma unroll
    for (int j = 0; j < 4; j++) {
        uint32_t v = x[threadIdx.x * 4 + j];
        uint32_t lo = v & 0xffffu;
        uint32_t e = (lo >> 7) & 0xffu;
        if (lo != 0u && e >= 110u && e <= 135u) c++;
    }
#pragma unroll
    for (int off = 32; off; off >>= 1) c += __shfl_down(c, off);
    if ((threadIdx.x & 63) == 0) red[threadIdx.x >> 6] = c;
    __syncthreads();
    if (threadIdx.x == 0)
        *flag = (red[0] + red[1] + red[2] + red[3] > 614) ? 1 : 0;   // 1=bf16, 0=fp32
}

// vectorized conversion, 4 elements per thread
__global__ __launch_bounds__(256) void to_bf16(
    const void* __restrict__ src, u16* __restrict__ dst, int n4,
    const int* __restrict__ flag)
{
    int i = blockIdx.x * 256 + threadIdx.x;
    const int stride = gridDim.x * 256;
    if (*flag != 0) {
        const uint2* s = (const uint2*)src;
        uint2* d = (uint2*)dst;
        for (; i < n4; i += stride) d[i] = s[i];
    } else {
        const float4* s = (const float4*)src;
        for (; i < n4; i += stride) {
            float4 v = s[i];
            ushort4 o = { f2bf(v.x), f2bf(v.y), f2bf(v.z), f2bf(v.w) };
            *(ushort4*)(dst + (size_t)i * 4) = o;
        }
    }
}

// m97-pattern MFMA GEMM, generalized to rectangular tiles:
// C = A (MxK bf16 rm) * B^T (B NxK rm), fp32 accum. global_load_lds width-16
// staging into unpadded [BM][64]/[BN][64] LDS tiles with XOR swizzle ->
// conflict-free stride-64 fragment reads. 4 waves in 2x2 over (BM x BN).
// MODE 0 (128x128): scatter q [b,h,t,d] (x0.125), k [b,h,t,d], vT [b,h,d,t].
// MODE 1 (128x64): row-major C; fp32 (flag==0) or bf16 path, full-line stores.
//   Rect tile fixes R6's mistake: BM=128 keeps arithmetic intensity up while
//   BN=64 keeps the grid at 512 blocks (2/CU) for the 4096x1024 out-proj.
template<int BM, int BN, int MODE>
__global__ __launch_bounds__(256, 3) void gemm_bt_mfma(
    const u16* __restrict__ A, const u16* __restrict__ B,
    int N, int K,
    u16* __restrict__ qo, u16* __restrict__ ko, u16* __restrict__ vt,
    u16* __restrict__ outb16, float* __restrict__ outf32,
    const int* __restrict__ flag)
{
    constexpr int WM = BM / 2;
    constexpr int WN = BN / 2;
    constexpr int MI = WM / 16;
    constexpr int NI = WN / 16;
    constexpr int IA = BM / 32;
    constexpr int IB = BN / 32;
    constexpr int ST = (BM + BN) * 64 * 2;
    constexpr int E16 = (MODE == 0) ? 4 * WM * 72 * 2 : 4 * WM * (WN + 8) * 2;
    constexpr int EF = (MODE == 1) ? 4 * WM * (WN + 4) * 4 : 0;
    constexpr int SB0 = (ST > E16 ? ST : E16);
    constexpr int SB = SB0 > EF ? SB0 : EF;
    __shared__ u16 smem[SB / 2];
    u16* As = smem;            // [BM][64]
    u16* Bs = smem + BM * 64;  // [BN][64]
    const int tid = threadIdx.x;
    const int bm = blockIdx.y * BM, bn = blockIdx.x * BN;
    const int w = tid >> 6, lane = tid & 63;
    const int wm = (w >> 1) * WM, wn = (w & 1) * WN;
    const int n16 = lane & 15, quad = lane >> 4;
    const int l8 = lane >> 3, c8 = lane & 7;

    f32x4 acc[MI][NI];
#pragma unroll
    for (int mi = 0; mi < MI; mi++)
#pragma unroll
        for (int ni = 0; ni < NI; ni++) acc[mi][ni] = (f32x4){0.f, 0.f, 0.f, 0.f};

    const int KT = K >> 6;
    for (int kt = 0; kt < KT; kt++) {
        const int k0 = kt << 6;
#pragma unroll
        for (int i = 0; i < IA; i++) {
            int rowblk = (i * 4 + w) * 8;
            int row = rowblk + l8;
            int gcol = (c8 ^ l8) * 8;   // XOR swizzle
            gl_lds16(A + (size_t)(bm + row) * K + k0 + gcol, As + rowblk * 64);
        }
#pragma unroll
        for (int i = 0; i < IB; i++) {
            int rowblk = (i * 4 + w) * 8;
            int row = rowblk + l8;
            int gcol = (c8 ^ l8) * 8;   // XOR swizzle
            gl_lds16(B + (size_t)(bn + row) * K + k0 + gcol, Bs + rowblk * 64);
        }
        __syncthreads();
#pragma unroll
        for (int ks = 0; ks < 2; ks++) {
            bf16x8 af[MI], bfr[NI];
#pragma unroll
            for (int mi = 0; mi < MI; mi++) {
                int row = wm + mi * 16 + n16;
                af[mi] = *(const bf16x8*)(As + row * 64 + (((ks * 4 + quad) ^ (n16 & 7)) * 8));
            }
#pragma unroll
            for (int ni = 0; ni < NI; ni++) {
                int row = wn + ni * 16 + n16;
                bfr[ni] = *(const bf16x8*)(Bs + row * 64 + (((ks * 4 + quad) ^ (n16 & 7)) * 8));
            }
#pragma unroll
            for (int mi = 0; mi < MI; mi++)
#pragma unroll
                for (int ni = 0; ni < NI; ni++)
                    acc[mi][ni] = __builtin_amdgcn_mfma_f32_16x16x32_bf16(
                        af[mi], bfr[ni], acc[mi][ni], 0, 0, 0);
        }
        __syncthreads();
    }

    // Epilogues: per-wave LDS transpose -> full-line stores.
    // C/D layout: col = n16, row = quad*4 + r (HW-verified m89/m91).
    if constexpr (MODE == 0) {
        u16* ep = smem + w * (WM * 72);
        const int which = (bn + wn) >> 10;            // 0=q 1=k 2=v (wave-uniform)
        const int hq = ((bn + wn) & 1023) >> 6;
        const int bb = (bm + wm) >> 11;
        const int tb = (bm + wm) & (T_SEQ - 1);
        if (which == 2) {
#pragma unroll
            for (int mi = 0; mi < MI; mi++)
#pragma unroll
                for (int ni = 0; ni < NI; ni++)
#pragma unroll
                    for (int r = 0; r < 4; r++)
                        ep[(ni * 16 + n16) * 72 + mi * 16 + quad * 4 + r] = f2bf(acc[mi][ni][r]);
            asm volatile("s_waitcnt lgkmcnt(0)" ::: "memory");
            u16* dst = vt + ((size_t)(bb * NHEAD + hq) * HDIM) * T_SEQ + tb;
#pragma unroll
            for (int it = 0; it < 8; it++) {
                int row = it * 8 + l8, col = c8 * 8;
                bf16x8 v = *(const bf16x8*)(ep + row * 72 + col);
                *(bf16x8*)(dst + (size_t)row * T_SEQ + col) = v;
            }
        } else {
            const float sc = which ? 1.f : 0.125f;
#pragma unroll
            for (int mi = 0; mi < MI; mi++)
#pragma unroll
                for (int ni = 0; ni < NI; ni++)
#pragma unroll
                    for (int r = 0; r < 4; r++)
                        ep[(mi * 16 + quad * 4 + r) * 72 + ni * 16 + n16] = f2bf(acc[mi][ni][r] * sc);
            asm volatile("s_waitcnt lgkmcnt(0)" ::: "memory");
            u16* dst = (which ? ko : qo) + ((size_t)(bb * NHEAD + hq) * T_SEQ + tb) * HDIM;
#pragma unroll
            for (int it = 0; it < 8; it++) {
                int row = it * 8 + l8, col = c8 * 8;
                bf16x8 v = *(const bf16x8*)(ep + row * 72 + col);
                *(bf16x8*)(dst + (size_t)row * HDIM + col) = v;
            }
        }
    } else {
        if (*flag == 0) {
            float* epf = (float*)smem + w * (WM * (WN + 4));
#pragma unroll
            for (int mi = 0; mi < MI; mi++)
#pragma unroll
                for (int ni = 0; ni < NI; ni++)
#pragma unroll
                    for (int r = 0; r < 4; r++)
                        epf[(mi * 16 + quad * 4 + r) * (WN + 4) + ni * 16 + n16] = acc[mi][ni][r];
            asm volatile("s_waitcnt lgkmcnt(0)" ::: "memory");
            constexpr int LPR = WN / 4;
            constexpr int RPI = 64 / LPR;
#pragma unroll
            for (int it = 0; it < WM / RPI; it++) {
                int row = it * RPI + lane / LPR, col = (lane % LPR) * 4;
                float4 v = *(const float4*)(epf + row * (WN + 4) + col);
                *(float4*)(outf32 + (size_t)(bm + wm + row) * N + bn + wn + col) = v;
            }
        } else {
            u16* ep = smem + w * (WM * (WN + 8));
#pragma unroll
            for (int mi = 0; mi < MI; mi++)
#pragma unroll
                for (int ni = 0; ni < NI; ni++)
#pragma unroll
                    for (int r = 0; r < 4; r++)
                        ep[(mi * 16 + quad * 4 + r) * (WN + 8) + ni * 16 + n16] = f2bf(acc[mi][ni][r]);
            asm volatile("s_waitcnt lgkmcnt(0)" ::: "memory");
            constexpr int LPR = WN / 8;
            constexpr int RPI = 64 / LPR;
#pragma unroll
            for (int it = 0; it < WM / RPI; it++) {
                int row = it * RPI + lane / LPR, col = (lane % LPR) * 8;
                bf16x8 v = *(const bf16x8*)(ep + row * (WN + 8) + col);
                *(bf16x8*)(outb16 + (size_t)(bm + wm + row) * N + bn + wn + col) = v;
            }
        }
    }
}

// MFMA flash attention — R1 kernel (best measured, reproduced twice: 47.6 /
// 47.0 us) + s_setprio around the MFMA clusters (learn_hip m191: attn +4-7%
// when multiple independent blocks share a CU at different phases — exactly
// this regime: 2 x 8-wave blocks/CU with unsynchronized convoys).
// Everything else byte-identical to R1. Eight redesign attempts (R2-R8:
// split-K, uniform makespan, pairing, 2x rows/wave, in-register softmax)
// all measured slower; this structure is the local optimum.
__global__ __launch_bounds__(512, 4) void attn_mfma(
    const u16* __restrict__ qb, const u16* __restrict__ kb,
    const u16* __restrict__ vt, u16* __restrict__ ob)
{
    __shared__ u16 Ks[64 * 64];        // [t_local][d], XOR-swizzled chunks
    __shared__ u16 Vs[64 * 64];        // [d][t_local], XOR-swizzled chunks
    __shared__ u16 Plds[8][16][72];
    const int bidx = blockIdx.x;       // 0..511
    const int c = bidx & 255;
    const int rr = bidx >> 8;          // round 0/1
    const int bh = c & 31;             // xcd = bidx&7 = bh&7 (pinned)
    const int jm = c >> 5;             // 0..7
    const int t = rr ? (15 - jm) : jm; // q-block 0..15
    const int w = threadIdx.x >> 6, lane = threadIdx.x & 63;
    const int n16 = lane & 15, quad = lane >> 4;
    const int l8 = lane >> 3, c8 = lane & 7;
    const size_t baseK = (size_t)bh * T_SEQ * HDIM;   // [t][d]
    const size_t baseV = (size_t)bh * HDIM * T_SEQ;   // [d][t]
    const int b = bh >> 4, head = bh & 15;

    bf16x8 ones;
#pragma unroll
    for (int e = 0; e < 8; e++) ones[e] = (short)0x3F80;   // bf16 1.0

    // 8 waves stage one 64x64 K tile + one 64x64 V^T tile: wave w covers rows
    // w*8..w*8+7 (1 KB per gl_lds16 instr = 8 rows of 128 B).
    auto stage = [&](int kt) {
        int row = w * 8 + l8;
        int gc = (c8 ^ l8) * 8;        // XOR swizzle
        gl_lds16(kb + baseK + (size_t)(kt * 64 + row) * HDIM + gc, Ks + (w * 8) * 64);
        gl_lds16(vt + baseV + (size_t)row * T_SEQ + (size_t)kt * 64 + gc, Vs + (w * 8) * 64);
    };

    const int qrow = t * 128 + w * 16;
    bf16x8 qf[2];
#pragma unroll
    for (int ks = 0; ks < 2; ks++)
        qf[ks] = *(const bf16x8*)(qb + baseK + (size_t)(qrow + n16) * HDIM + ks * 32 + quad * 8);

    f32x4 accO[4];
#pragma unroll
    for (int st = 0; st < 4; st++) accO[st] = (f32x4){0.f, 0.f, 0.f, 0.f};
    f32x4 accL = (f32x4){0.f, 0.f, 0.f, 0.f};

    const int ktmax = 2 * t + 1;           // block's last staged tile
    const int kend  = 2 * t + (w >> 2);    // this wave's diagonal tile

    stage(0);
    for (int kt = 0; kt <= ktmax; kt++) {
        __syncthreads();                   // stage(kt) complete (drains vmcnt)

        const bool act = (kt <= kend);     // wave-uniform
        bf16x8 kf[2][4], vf[2][4];
        if (act) {
#pragma unroll
            for (int st = 0; st < 4; st++)
#pragma unroll
                for (int ks = 0; ks < 2; ks++) {
                    int off = (st * 16 + n16) * 64 + (((ks * 4 + quad) ^ (n16 & 7)) * 8);
                    kf[ks][st] = *(const bf16x8*)(Ks + off);
                    vf[ks][st] = *(const bf16x8*)(Vs + off);
                }
        }
        __syncthreads();                   // fragments in registers; K/V LDS free

        if (kt < ktmax) stage(kt + 1);     // async, lands during compute below

        if (act) {
            f32x4 S[4];
#pragma unroll
            for (int st = 0; st < 4; st++) S[st] = (f32x4){0.f, 0.f, 0.f, 0.f};
            __builtin_amdgcn_s_setprio(1);
#pragma unroll
            for (int st = 0; st < 4; st++)
#pragma unroll
                for (int ks = 0; ks < 2; ks++)
                    S[st] = __builtin_amdgcn_mfma_f32_16x16x32_bf16(qf[ks], kf[ks][st], S[st], 0, 0, 0);
            __builtin_amdgcn_s_setprio(0);
            if (kt == kend) {
                int qloc = (w & 3) * 16 + quad * 4;
#pragma unroll
                for (int st = 0; st < 4; st++) {
                    int kloc = st * 16 + n16;
#pragma unroll
                    for (int r = 0; r < 4; r++)
                        if (kloc > qloc + r) S[st][r] = -INFINITY;
                }
            }
#pragma unroll
            for (int st = 0; st < 4; st++)
#pragma unroll
                for (int r = 0; r < 4; r++) {
                    float pv = exp2f(__builtin_fmaf(S[st][r], 1.44269504f, -14.4269504f));
                    Plds[w][quad * 4 + r][st * 16 + n16] = (u16)(__float_as_uint(pv) >> 16);
                }
            asm volatile("s_waitcnt lgkmcnt(0)" ::: "memory");
            bf16x8 pf[2];
#pragma unroll
            for (int ks = 0; ks < 2; ks++)
                pf[ks] = *(const bf16x8*)(&Plds[w][n16][ks * 32 + quad * 8]);
            __builtin_amdgcn_s_setprio(1);
#pragma unroll
            for (int st = 0; st < 4; st++)
#pragma unroll
                for (int ks = 0; ks < 2; ks++)
                    accO[st] = __builtin_amdgcn_mfma_f32_16x16x32_bf16(pf[ks], vf[ks][st], accO[st], 0, 0, 0);
#pragma unroll
            for (int ks = 0; ks < 2; ks++)
                accL = __builtin_amdgcn_mfma_f32_16x16x32_bf16(pf[ks], ones, accL, 0, 0, 0);
            __builtin_amdgcn_s_setprio(0);
        }
    }

    // epilogue: normalize, transpose via Plds (wave-private), line stores
#pragma unroll
    for (int r = 0; r < 4; r++) {
        float inv = 1.f / accL[r];
#pragma unroll
        for (int st = 0; st < 4; st++)
            Plds[w][quad * 4 + r][st * 16 + n16] = f2bf(accO[st][r] * inv);
    }
    asm volatile("s_waitcnt lgkmcnt(0)" ::: "memory");
    u16* dst = ob + ((size_t)(b * T_SEQ + qrow)) * 1024 + head * HDIM;
#pragma unroll
    for (int it = 0; it < 2; it++) {
        int row = it * 8 + l8, col = c8 * 8;
        bf16x8 v = *(const bf16x8*)(&Plds[w][row][col]);
        *(bf16x8*)(dst + (size_t)row * 1024 + col) = v;
    }
}

extern "C" void kernel_launch(void* const* d_in, const int* in_sizes, int n_in,
                              void* d_out, int out_size, void* d_ws, size_t ws_size,
                              hipStream_t stream) {
    const void* x    = d_in[0];   // (2,2048,1024)
    const void* Wqkv = d_in[1];   // (3072,1024)
    const void* Wout = d_in[2];   // (1024,1024)

    const int Mtok = NB * T_SEQ;                                  // 4096
    const size_t n_x    = (size_t)Mtok * 1024;
    const size_t n_wqkv = (size_t)3072 * 1024;
    const size_t n_wout = (size_t)1024 * 1024;
    const size_t qkv_elems = (size_t)NB * NHEAD * T_SEQ * HDIM;   // 4,194,304

    u16* xb    = (u16*)d_ws;
    u16* wqkvb = xb + n_x;
    u16* woutb = wqkvb + n_wqkv;
    u16* qb    = woutb + n_wout;
    u16* kb    = qb + qkv_elems;
    u16* vt    = kb + qkv_elems;   // V stored transposed [b,h,d,t]
    u16* obuf  = vt + qkv_elems;
    int* flag  = (int*)(obuf + qkv_elems);

    detect_dtype<<<1, 256, 0, stream>>>((const uint32_t*)x, flag);

    to_bf16<<<1024, 256, 0, stream>>>(x,    xb,    (int)(n_x / 4),    flag);
    to_bf16<<<1024, 256, 0, stream>>>(Wqkv, wqkvb, (int)(n_wqkv / 4), flag);
    to_bf16<<<512,  256, 0, stream>>>(Wout, woutb, (int)(n_wout / 4), flag);

    gemm_bt_mfma<128, 128, 0><<<dim3(3072 / 128, Mtok / 128), 256, 0, stream>>>(
        xb, wqkvb, 3072, 1024, qb, kb, vt, nullptr, nullptr, flag);

    // 512 blocks x 512 threads: 32 bh x 16 q-blocks of 128 rows, 8 waves each
    // (R1 configuration, best measured attn: 47.0-47.6 us) + setprio
    attn_mfma<<<dim3(NB * NHEAD * (T_SEQ / 128)), 512, 0, stream>>>(qb, kb, vt, obuf);

    // out-projection on a rectangular 128x64 tile: 512 blocks (2/CU), higher
    // arithmetic intensity than 64^2 without R6's 256-block occupancy cliff
    gemm_bt_mfma<128, 64, 1><<<dim3(1024 / 64, Mtok / 128), 256, 0, stream>>>(
        obuf, woutb, 1024, 1024, nullptr, nullptr, nullptr,
        (u16*)d_out, (float*)d_out, flag);
}